// Round 1
// baseline (1052.351 us; speedup 1.0000x reference)
//
#include <hip/hip_runtime.h>

// ---------- types / helpers ----------
typedef __bf16 bf16x8 __attribute__((ext_vector_type(8)));
typedef float  f32x4  __attribute__((ext_vector_type(4)));

#define EPSC 1e-6f

__device__ __forceinline__ unsigned short f2bf(float f) {
  union { float f; unsigned int u; } c; c.f = f;
  unsigned int u = c.u;
  u = u + 0x7FFFu + ((u >> 16) & 1u);   // RNE
  return (unsigned short)(u >> 16);
}
__device__ __forceinline__ float bf2f(unsigned short h) {
  union { unsigned int u; float f; } c; c.u = ((unsigned int)h) << 16;
  return c.f;
}
__device__ __forceinline__ void gl_lds16(const unsigned short* g, unsigned short* l) {
  __builtin_amdgcn_global_load_lds((const __attribute__((address_space(1))) void*)g,
                                   (__attribute__((address_space(3))) void*)l, 16, 0, 0);
}

// ---------- K1: Cayley — build L, Gauss-Jordan invert, Qt = Linv*L^T - eps*Linv ----------
// grid 24 blocks x 256 threads, 64KB dynamic LDS
__global__ void __launch_bounds__(256) cayley_k(const float* __restrict__ qR,
                                               const float* __restrict__ kR,
                                               const float* __restrict__ vR,
                                               float* __restrict__ wsL,
                                               float* __restrict__ wsQt) {
  extern __shared__ float A_s[];      // [128][128]
  float4* A4 = (float4*)A_s;          // [128][32]
  const int m = blockIdx.x;           // 0..23
  const float* R = (m < 8 ? qR : (m < 16 ? kR : vR)) + (size_t)(m & 7) * 16384;
  float* Lg = wsL  + (size_t)m * 16384;
  float* Qt = wsQt + (size_t)m * 16384;
  const int tid = threadIdx.x;

  // phase 1: L = I - S + eps*I, S = 0.5*(R - R^T); keep in LDS + stash to ws
  for (int idx = tid; idx < 16384; idx += 256) {
    int i = idx >> 7, j = idx & 127;
    float s = 0.5f * (R[idx] - R[j * 128 + i]);
    float v = ((i == j) ? (1.0f + EPSC) : 0.0f) - s;
    A_s[idx] = v;
    Lg[idx] = v;
  }
  __syncthreads();

  // phase 2: in-place Gauss-Jordan inverse (no pivoting; sym part of L is SPD)
  const int c = tid & 31;     // float4 chunk within row
  const int rg = tid >> 5;    // row group 0..7
  for (int k = 0; k < 128; ++k) {
    __syncthreads();                       // prev pivot's updates complete
    if (tid < 32) {                        // wave0 scales row k
      float ip = 1.0f / A_s[k * 128 + k];  // lockstep: read before write, safe
      float4 v = A4[k * 32 + tid];
      v.x *= ip; v.y *= ip; v.z *= ip; v.w *= ip;
      if (tid == (k >> 2)) {
        int k3 = k & 3;
        if (k3 == 0) v.x = ip; else if (k3 == 1) v.y = ip;
        else if (k3 == 2) v.z = ip; else v.w = ip;
      }
      A4[k * 32 + tid] = v;
    }
    __syncthreads();                       // row k ready
    float4 rk = A4[k * 32 + c];
    const int kc = k >> 2, k3 = k & 3;
    float ipv = (k3 == 0) ? rk.x : (k3 == 1) ? rk.y : (k3 == 2) ? rk.z : rk.w; // == 1/p where c==kc
#pragma unroll
    for (int pass = 0; pass < 16; ++pass) {
      int i = pass * 8 + rg;
      if (i != k) {
        float mi = A_s[i * 128 + k];       // same-wave lockstep: all reads before writes
        float4 v = A4[i * 32 + c];
        v.x -= mi * rk.x; v.y -= mi * rk.y; v.z -= mi * rk.z; v.w -= mi * rk.w;
        if (c == kc) {
          float fx = -mi * ipv;
          if (k3 == 0) v.x = fx; else if (k3 == 1) v.y = fx;
          else if (k3 == 2) v.z = fx; else v.w = fx;
        }
        A4[i * 32 + c] = v;
      }
    }
  }
  __syncthreads();   // A_s == Linv

  // phase 3: Qt[i][j] = sum_t Linv[i][t]*Lg[j][t] - eps*Linv[i][j]
  const int ti = tid >> 4, tj = tid & 15;
  const int i0 = ti * 8, j0 = tj * 8;
  float acc[8][8];
#pragma unroll
  for (int r = 0; r < 8; ++r)
#pragma unroll
    for (int s = 0; s < 8; ++s) acc[r][s] = 0.f;

  for (int tc = 0; tc < 32; ++tc) {
    float4 b4[8];
#pragma unroll
    for (int s = 0; s < 8; ++s)
      b4[s] = *(const float4*)&Lg[(size_t)(j0 + s) * 128 + tc * 4];
#pragma unroll
    for (int r = 0; r < 8; ++r) {
      float4 a4 = A4[(i0 + r) * 32 + tc];
#pragma unroll
      for (int s = 0; s < 8; ++s)
        acc[r][s] += a4.x * b4[s].x + a4.y * b4[s].y + a4.z * b4[s].z + a4.w * b4[s].w;
    }
  }
#pragma unroll
  for (int r = 0; r < 8; ++r)
#pragma unroll
    for (int s = 0; s < 8; ++s) {
      float v = acc[r][s] - EPSC * A_s[(i0 + r) * 128 + j0 + s];
      Qt[(size_t)(i0 + r) * 128 + j0 + s] = v;
    }
}

// ---------- K2: filt[o][n*128+c] = sum_b W[o][n*128+b] * Qt_m[c][b]  (bf16 out) ----------
// grid (24, 16) x 256: block = (matrix m, 64-row o-tile)
__global__ void __launch_bounds__(256) filt_k(const float* __restrict__ W,
                                              const float* __restrict__ wsQt,
                                              unsigned short* __restrict__ filt) {
  __shared__ unsigned short Qs[128 * 136];    // bf16, padded stride
  const int m = blockIdx.x;                   // 0..23
  const int ot = blockIdx.y;                  // 0..15
  const int mset = m >> 3, n = m & 7;
  const float* Qt = wsQt + (size_t)m * 16384;
  const int tid = threadIdx.x;

  for (int idx = tid; idx < 16384; idx += 256) {
    int i = idx >> 7, j = idx & 127;
    Qs[i * 136 + j] = f2bf(Qt[idx]);
  }
  __syncthreads();

  const int ol = tid & 63, cg = tid >> 6;     // cg uniform per wave -> LDS broadcast reads
  const int go = mset * 1024 + ot * 64 + ol;
  const float* Wrow = W + (size_t)go * 1024 + n * 128;

  float acc[32];
#pragma unroll
  for (int i = 0; i < 32; ++i) acc[i] = 0.f;

  for (int b4 = 0; b4 < 32; ++b4) {
    float4 w4 = *(const float4*)(Wrow + b4 * 4);
#pragma unroll
    for (int cc = 0; cc < 32; ++cc) {
      int cidx = cg * 32 + cc;
      ushort4 q4 = *(const ushort4*)&Qs[cidx * 136 + b4 * 4];
      acc[cc] += w4.x * bf2f(q4.x) + w4.y * bf2f(q4.y)
               + w4.z * bf2f(q4.z) + w4.w * bf2f(q4.w);
    }
  }
  unsigned short* dst = filt + (size_t)go * 1024 + n * 128 + cg * 32;
#pragma unroll
  for (int g2 = 0; g2 < 8; ++g2) {
    ushort4 o;
    o.x = f2bf(acc[g2 * 4 + 0]); o.y = f2bf(acc[g2 * 4 + 1]);
    o.z = f2bf(acc[g2 * 4 + 2]); o.w = f2bf(acc[g2 * 4 + 3]);
    *(ushort4*)(dst + g2 * 4) = o;
  }
}

// ---------- K3: x fp32 -> bf16 ----------
__global__ void __launch_bounds__(256) cvt_k(const float4* __restrict__ in,
                                             ushort4* __restrict__ out, int n4) {
  int i = blockIdx.x * 256 + threadIdx.x;
  int stride = gridDim.x * 256;
  for (; i < n4; i += stride) {
    float4 v = in[i];
    ushort4 o;
    o.x = f2bf(v.x); o.y = f2bf(v.y); o.z = f2bf(v.z); o.w = f2bf(v.w);
    out[i] = o;
  }
}

// ---------- K4: C[M,N] = A[M,K] @ B[N,K]^T + bias, bf16 MFMA (m97 structure) ----------
// M=32768, N=3072, K=1024. grid (24, 256) x 256 threads.
__global__ void __launch_bounds__(256) gemm_k(const unsigned short* __restrict__ Ax,
                                              const unsigned short* __restrict__ Bf,
                                              const float* __restrict__ bias,
                                              float* __restrict__ C) {
  __shared__ unsigned short As[128 * 32];   // 8KB
  __shared__ unsigned short Bs[128 * 32];   // 8KB
  const int tid = threadIdx.x;
  const int bx = blockIdx.x;                // N-tile 0..23
  const int by = blockIdx.y;                // M-tile 0..255
  const int lane = tid & 63, wave = tid >> 6;
  const int wm = wave & 1, wn = wave >> 1;
  const int quad = lane >> 4, l16 = lane & 15;
  const long mbase = (long)by * 128;
  const long nbase = (long)bx * 128;

  f32x4 acc[4][4];
#pragma unroll
  for (int i = 0; i < 4; ++i)
#pragma unroll
    for (int j = 0; j < 4; ++j) {
      acc[i][j][0] = 0.f; acc[i][j][1] = 0.f; acc[i][j][2] = 0.f; acc[i][j][3] = 0.f;
    }

  // staging map: chunk q (0..511) -> row q>>2, col16 q&3; LDS offset q*16B (wave-uniform base + lane*16)
  const int q0 = tid, q1 = 256 + tid;
  const int row0 = q0 >> 2, c0 = (q0 & 3) * 8;
  const int row1 = q1 >> 2, c1 = (q1 & 3) * 8;
  const unsigned short* a0 = Ax + (mbase + row0) * 1024 + c0;
  const unsigned short* a1 = Ax + (mbase + row1) * 1024 + c1;
  const unsigned short* b0 = Bf + (nbase + row0) * 1024 + c0;
  const unsigned short* b1 = Bf + (nbase + row1) * 1024 + c1;
  unsigned short* lA0 = &As[q0 * 8]; unsigned short* lA1 = &As[q1 * 8];
  unsigned short* lB0 = &Bs[q0 * 8]; unsigned short* lB1 = &Bs[q1 * 8];

  for (int kk = 0; kk < 1024; kk += 32) {
    gl_lds16(a0 + kk, lA0);
    gl_lds16(a1 + kk, lA1);
    gl_lds16(b0 + kk, lB0);
    gl_lds16(b1 + kk, lB1);
    __syncthreads();          // compiler emits vmcnt(0) drain before barrier

    bf16x8 af[4], bf[4];
#pragma unroll
    for (int mi = 0; mi < 4; ++mi)
      af[mi] = *(const bf16x8*)&As[(wm * 64 + mi * 16 + l16) * 32 + quad * 8];
#pragma unroll
    for (int ni = 0; ni < 4; ++ni)
      bf[ni] = *(const bf16x8*)&Bs[(wn * 64 + ni * 16 + l16) * 32 + quad * 8];
#pragma unroll
    for (int mi = 0; mi < 4; ++mi)
#pragma unroll
      for (int ni = 0; ni < 4; ++ni)
        acc[mi][ni] = __builtin_amdgcn_mfma_f32_16x16x32_bf16(af[mi], bf[ni], acc[mi][ni], 0, 0, 0);
    __syncthreads();
  }

  // epilogue: D row = quad*4 + r (M dim), col = l16 (N dim)
#pragma unroll
  for (int ni = 0; ni < 4; ++ni) {
    long gcol = nbase + wn * 64 + ni * 16 + l16;
    float bv = bias[gcol];
#pragma unroll
    for (int mi = 0; mi < 4; ++mi) {
      long grow = mbase + wm * 64 + mi * 16 + quad * 4;
#pragma unroll
      for (int r = 0; r < 4; ++r)
        C[(grow + r) * 3072 + gcol] = acc[mi][ni][r] + bv;
    }
  }
}

// ---------- launcher ----------
extern "C" void kernel_launch(void* const* d_in, const int* in_sizes, int n_in,
                              void* d_out, int out_size, void* d_ws, size_t ws_size,
                              hipStream_t stream) {
  const float* W    = (const float*)d_in[0];  // [3072,1024]
  const float* bias = (const float*)d_in[1];  // [3072]
  const float* x    = (const float*)d_in[2];  // [8,4096,1024]
  const float* qR   = (const float*)d_in[3];  // [8,128,128]
  const float* kR   = (const float*)d_in[4];
  const float* vR   = (const float*)d_in[5];
  float* out = (float*)d_out;                 // [8,4096,3072]

  char* ws = (char*)d_ws;
  float* wsL           = (float*)(ws);                       // 1.5 MB
  float* wsQt          = (float*)(ws + 1572864);             // 1.5 MB
  unsigned short* wsF  = (unsigned short*)(ws + 3145728);    // 6 MB  (filt bf16)
  unsigned short* wsX  = (unsigned short*)(ws + 9437184);    // 64 MB (x bf16)

  cayley_k<<<24, 256, 65536, stream>>>(qR, kR, vR, wsL, wsQt);
  filt_k<<<dim3(24, 16), 256, 0, stream>>>(W, wsQt, wsF);
  cvt_k<<<4096, 256, 0, stream>>>((const float4*)x, (ushort4*)wsX, 33554432 / 4);
  gemm_k<<<dim3(24, 256), 256, 0, stream>>>(wsX, wsF, bias, out);
}

// Round 2
// 913.472 us; speedup vs baseline: 1.1520x; 1.1520x over previous
//
#include <hip/hip_runtime.h>

// ---------- types / helpers ----------
typedef __bf16 bf16x8 __attribute__((ext_vector_type(8)));
typedef float  f32x4  __attribute__((ext_vector_type(4)));

#define EPSC 1e-6f

__device__ __forceinline__ unsigned short f2bf(float f) {
  union { float f; unsigned int u; } c; c.f = f;
  unsigned int u = c.u;
  u = u + 0x7FFFu + ((u >> 16) & 1u);   // RNE
  return (unsigned short)(u >> 16);
}
__device__ __forceinline__ float bf2f(unsigned short h) {
  union { unsigned int u; float f; } c; c.u = ((unsigned int)h) << 16;
  return c.f;
}
__device__ __forceinline__ void gl_lds16(const unsigned short* g, unsigned short* l) {
  __builtin_amdgcn_global_load_lds((const __attribute__((address_space(1))) void*)g,
                                   (__attribute__((address_space(3))) void*)l, 16, 0, 0);
}

// ---------- K1: fused Cayley (blocks 0..23) + x fp32->bf16 convert (blocks 24+) ----------
// 512 threads, 64KB dynamic LDS.
// Cayley: L = I - S + eps*I; Gauss-Jordan invert in LDS (register-prefetched,
// predicated, no divergent branches); Qt = Linv*L^T - eps*Linv.
__global__ void __launch_bounds__(512) cayley_cvt_k(const float* __restrict__ qR,
                                                    const float* __restrict__ kR,
                                                    const float* __restrict__ vR,
                                                    float* __restrict__ wsL,
                                                    float* __restrict__ wsQt,
                                                    const float4* __restrict__ xin,
                                                    ushort4* __restrict__ xbf,
                                                    int n4) {
  extern __shared__ float A_s[];      // [128][128]
  const int tid = threadIdx.x;

  if (blockIdx.x >= 24) {
    // ---- convert branch: grid-stride over x ----
    int i = (blockIdx.x - 24) * 512 + tid;
    int stride = (gridDim.x - 24) * 512;
    for (; i < n4; i += stride) {
      float4 v = xin[i];
      ushort4 o;
      o.x = f2bf(v.x); o.y = f2bf(v.y); o.z = f2bf(v.z); o.w = f2bf(v.w);
      xbf[i] = o;
    }
    return;
  }

  float4* A4 = (float4*)A_s;          // [128][32]
  const int m = blockIdx.x;           // 0..23
  const float* R = (m < 8 ? qR : (m < 16 ? kR : vR)) + (size_t)(m & 7) * 16384;
  float* Lg = wsL  + (size_t)m * 16384;
  float* Qt = wsQt + (size_t)m * 16384;

  // phase 1: build L in LDS and stash to ws
  for (int idx = tid; idx < 16384; idx += 512) {
    int i = idx >> 7, j = idx & 127;
    float s = 0.5f * (R[idx] - R[j * 128 + i]);
    float v = ((i == j) ? (1.0f + EPSC) : 0.0f) - s;
    A_s[idx] = v;
    Lg[idx] = v;
  }

  // phase 2: in-place Gauss-Jordan inverse (no pivoting; sym part of L is SPD)
  const int c = tid & 31;     // float4 chunk within row
  const int rg = tid >> 5;    // half-wave row group 0..15; row i owned by rg == i%16
  for (int k = 0; k < 128; ++k) {
    __syncthreads();                       // prev pivot's writes complete
    if (tid < 32) {                        // one half-wave scales row k
      float ip = 1.0f / A_s[k * 128 + k];  // lockstep: read before write
      float4 v = A4[k * 32 + tid];
      v.x *= ip; v.y *= ip; v.z *= ip; v.w *= ip;
      if (tid == (k >> 2)) {
        int k3 = k & 3;
        if (k3 == 0) v.x = ip; else if (k3 == 1) v.y = ip;
        else if (k3 == 2) v.z = ip; else v.w = ip;
      }
      A4[k * 32 + tid] = v;
    }
    __syncthreads();                       // row k ready

    float4 rk = A4[k * 32 + c];
    const int kc = k >> 2, k3 = k & 3;
    const float ipv = (k3 == 0) ? rk.x : (k3 == 1) ? rk.y : (k3 == 2) ? rk.z : rk.w;

    // prefetch: batch all reads before any write (no cross-half-wave hazards:
    // row i is read/written only by half-wave rg==i%16; row k rewrite is bit-identical)
    float mi[8];
    float4 v[8];
#pragma unroll
    for (int p = 0; p < 8; ++p) mi[p] = A_s[(p * 16 + rg) * 128 + k];
#pragma unroll
    for (int p = 0; p < 8; ++p) v[p] = A4[(p * 16 + rg) * 32 + c];
#pragma unroll
    for (int p = 0; p < 8; ++p) {
      const int i = p * 16 + rg;
      const bool isk = (i == k);
      const float mm = isk ? 0.0f : mi[p];
      float4 w = v[p];
      w.x -= mm * rk.x; w.y -= mm * rk.y; w.z -= mm * rk.z; w.w -= mm * rk.w;
      if (c == kc && !isk) {
        const float fx = -mm * ipv;
        if (k3 == 0) w.x = fx; else if (k3 == 1) w.y = fx;
        else if (k3 == 2) w.z = fx; else w.w = fx;
      }
      A4[i * 32 + c] = w;
    }
  }
  __syncthreads();   // A_s == Linv

  // phase 3: Qt[i][j] = sum_t Linv[i][t]*Lg[j][t] - eps*Linv[i][j]
  const int ti = tid >> 4, tj = tid & 15;   // ti 0..31, tj 0..15
  const int i0 = ti * 4, j0 = tj * 8;
  float acc[4][8];
#pragma unroll
  for (int r = 0; r < 4; ++r)
#pragma unroll
    for (int s = 0; s < 8; ++s) acc[r][s] = 0.f;

  for (int tc = 0; tc < 32; ++tc) {
    float4 b4[8];
#pragma unroll
    for (int s = 0; s < 8; ++s)
      b4[s] = *(const float4*)&Lg[(size_t)(j0 + s) * 128 + tc * 4];
#pragma unroll
    for (int r = 0; r < 4; ++r) {
      float4 a4 = A4[(i0 + r) * 32 + tc];
#pragma unroll
      for (int s = 0; s < 8; ++s)
        acc[r][s] += a4.x * b4[s].x + a4.y * b4[s].y + a4.z * b4[s].z + a4.w * b4[s].w;
    }
  }
#pragma unroll
  for (int r = 0; r < 4; ++r)
#pragma unroll
    for (int s = 0; s < 8; ++s) {
      float v = acc[r][s] - EPSC * A_s[(i0 + r) * 128 + j0 + s];
      Qt[(size_t)(i0 + r) * 128 + j0 + s] = v;
    }
}

// ---------- K2: filt[o][n*128+c] = sum_b W[o][n*128+b] * Qt_m[c][b]  (bf16 out) ----------
// grid (24, 16) x 256: block = (matrix m, 64-row o-tile)
__global__ void __launch_bounds__(256) filt_k(const float* __restrict__ W,
                                              const float* __restrict__ wsQt,
                                              unsigned short* __restrict__ filt) {
  __shared__ unsigned short Qs[128 * 136];    // bf16, padded stride
  const int m = blockIdx.x;                   // 0..23
  const int ot = blockIdx.y;                  // 0..15
  const int mset = m >> 3, n = m & 7;
  const float* Qt = wsQt + (size_t)m * 16384;
  const int tid = threadIdx.x;

  for (int idx = tid; idx < 16384; idx += 256) {
    int i = idx >> 7, j = idx & 127;
    Qs[i * 136 + j] = f2bf(Qt[idx]);
  }
  __syncthreads();

  const int ol = tid & 63, cg = tid >> 6;     // cg uniform per wave -> LDS broadcast reads
  const int go = mset * 1024 + ot * 64 + ol;
  const float* Wrow = W + (size_t)go * 1024 + n * 128;

  float acc[32];
#pragma unroll
  for (int i = 0; i < 32; ++i) acc[i] = 0.f;

  for (int b4 = 0; b4 < 32; ++b4) {
    float4 w4 = *(const float4*)(Wrow + b4 * 4);
#pragma unroll
    for (int cc = 0; cc < 32; ++cc) {
      int cidx = cg * 32 + cc;
      ushort4 q4 = *(const ushort4*)&Qs[cidx * 136 + b4 * 4];
      acc[cc] += w4.x * bf2f(q4.x) + w4.y * bf2f(q4.y)
               + w4.z * bf2f(q4.z) + w4.w * bf2f(q4.w);
    }
  }
  unsigned short* dst = filt + (size_t)go * 1024 + n * 128 + cg * 32;
#pragma unroll
  for (int g2 = 0; g2 < 8; ++g2) {
    ushort4 o;
    o.x = f2bf(acc[g2 * 4 + 0]); o.y = f2bf(acc[g2 * 4 + 1]);
    o.z = f2bf(acc[g2 * 4 + 2]); o.w = f2bf(acc[g2 * 4 + 3]);
    *(ushort4*)(dst + g2 * 4) = o;
  }
}

// ---------- K3: C[M,N] = A[M,K] @ B[N,K]^T + bias, bf16 MFMA (m97 structure) ----------
// M=32768, N=3072, K=1024. grid (24, 256) x 256 threads.
__global__ void __launch_bounds__(256) gemm_k(const unsigned short* __restrict__ Ax,
                                              const unsigned short* __restrict__ Bf,
                                              const float* __restrict__ bias,
                                              float* __restrict__ C) {
  __shared__ unsigned short As[128 * 32];   // 8KB
  __shared__ unsigned short Bs[128 * 32];   // 8KB
  const int tid = threadIdx.x;
  const int bx = blockIdx.x;                // N-tile 0..23
  const int by = blockIdx.y;                // M-tile 0..255
  const int lane = tid & 63, wave = tid >> 6;
  const int wm = wave & 1, wn = wave >> 1;
  const int quad = lane >> 4, l16 = lane & 15;
  const long mbase = (long)by * 128;
  const long nbase = (long)bx * 128;

  f32x4 acc[4][4];
#pragma unroll
  for (int i = 0; i < 4; ++i)
#pragma unroll
    for (int j = 0; j < 4; ++j) {
      acc[i][j][0] = 0.f; acc[i][j][1] = 0.f; acc[i][j][2] = 0.f; acc[i][j][3] = 0.f;
    }

  const int q0 = tid, q1 = 256 + tid;
  const int row0 = q0 >> 2, c0 = (q0 & 3) * 8;
  const int row1 = q1 >> 2, c1 = (q1 & 3) * 8;
  const unsigned short* a0 = Ax + (mbase + row0) * 1024 + c0;
  const unsigned short* a1 = Ax + (mbase + row1) * 1024 + c1;
  const unsigned short* b0 = Bf + (nbase + row0) * 1024 + c0;
  const unsigned short* b1 = Bf + (nbase + row1) * 1024 + c1;
  unsigned short* lA0 = &As[q0 * 8]; unsigned short* lA1 = &As[q1 * 8];
  unsigned short* lB0 = &Bs[q0 * 8]; unsigned short* lB1 = &Bs[q1 * 8];

  for (int kk = 0; kk < 1024; kk += 32) {
    gl_lds16(a0 + kk, lA0);
    gl_lds16(a1 + kk, lA1);
    gl_lds16(b0 + kk, lB0);
    gl_lds16(b1 + kk, lB1);
    __syncthreads();

    bf16x8 af[4], bff[4];
#pragma unroll
    for (int mi = 0; mi < 4; ++mi)
      af[mi] = *(const bf16x8*)&As[(wm * 64 + mi * 16 + l16) * 32 + quad * 8];
#pragma unroll
    for (int ni = 0; ni < 4; ++ni)
      bff[ni] = *(const bf16x8*)&Bs[(wn * 64 + ni * 16 + l16) * 32 + quad * 8];
#pragma unroll
    for (int mi = 0; mi < 4; ++mi)
#pragma unroll
      for (int ni = 0; ni < 4; ++ni)
        acc[mi][ni] = __builtin_amdgcn_mfma_f32_16x16x32_bf16(af[mi], bff[ni], acc[mi][ni], 0, 0, 0);
    __syncthreads();
  }

  // epilogue: D row = quad*4 + r (M dim), col = l16 (N dim)
#pragma unroll
  for (int ni = 0; ni < 4; ++ni) {
    long gcol = nbase + wn * 64 + ni * 16 + l16;
    float bv = bias[gcol];
#pragma unroll
    for (int mi = 0; mi < 4; ++mi) {
      long grow = mbase + wm * 64 + mi * 16 + quad * 4;
#pragma unroll
      for (int r = 0; r < 4; ++r)
        C[(grow + r) * 3072 + gcol] = acc[mi][ni][r] + bv;
    }
  }
}

// ---------- launcher ----------
extern "C" void kernel_launch(void* const* d_in, const int* in_sizes, int n_in,
                              void* d_out, int out_size, void* d_ws, size_t ws_size,
                              hipStream_t stream) {
  const float* W    = (const float*)d_in[0];  // [3072,1024]
  const float* bias = (const float*)d_in[1];  // [3072]
  const float* x    = (const float*)d_in[2];  // [8,4096,1024]
  const float* qR   = (const float*)d_in[3];  // [8,128,128]
  const float* kR   = (const float*)d_in[4];
  const float* vR   = (const float*)d_in[5];
  float* out = (float*)d_out;                 // [8,4096,3072]

  char* ws = (char*)d_ws;
  float* wsL           = (float*)(ws);                       // 1.5 MB
  float* wsQt          = (float*)(ws + 1572864);             // 1.5 MB
  unsigned short* wsF  = (unsigned short*)(ws + 3145728);    // 6 MB  (filt bf16)
  unsigned short* wsX  = (unsigned short*)(ws + 9437184);    // 64 MB (x bf16)

  cayley_cvt_k<<<24 + 2048, 512, 65536, stream>>>(qR, kR, vR, wsL, wsQt,
                                                  (const float4*)x, (ushort4*)wsX,
                                                  33554432 / 4);
  filt_k<<<dim3(24, 16), 256, 0, stream>>>(W, wsQt, wsF);
  gemm_k<<<dim3(24, 256), 256, 0, stream>>>(wsX, wsF, bias, out);
}